// Round 3
// baseline (368.634 us; speedup 1.0000x reference)
//
#include <hip/hip_runtime.h>
#include <math.h>

#define T_TOK 16384   // 4*4096 tokens
#define NEXP  64

// Workspace layout (floats):
//   ws[0..63]   : expert load sums
//   ws[64]      : sum of z^2
//   ws[66]      : block-done counter (int)
//   ws[128 ..]  : w_t transposed gate weights [1024][64]
//
// d_out layout (floats, out_size = 65537):
//   [0, 32768)      top-2 renormalized scores [token][2]
//   [32768, 65536)  top-2 expert indices as floats [token][2]
//   [65536]         total_loss

// ---------------------------------------------------------------------------
// prep: tiled transpose gate_w [64][1024] -> w_t [1024][64]; zero accumulators
// ---------------------------------------------------------------------------
__global__ void moe_prep(const float* __restrict__ gw, float* __restrict__ ws) {
    __shared__ float tile[64][65];
    const int b = blockIdx.x;
    const int tid = threadIdx.x;         // 256
    if (b == 0 && tid < 128) ws[tid] = 0.f;
#pragma unroll
    for (int it = 0; it < 16; ++it) {
        int idx = it * 256 + tid;
        int e = idx >> 6, kk = idx & 63;
        tile[e][kk] = gw[e * 1024 + b * 64 + kk];
    }
    __syncthreads();
#pragma unroll
    for (int it = 0; it < 16; ++it) {
        int idx = it * 256 + tid;
        int kk = idx >> 6, e = idx & 63;
        ws[128 + (b * 64 + kk) * 64 + e] = tile[e][kk];
    }
}

// ---------------------------------------------------------------------------
// fold helpers: store/add 4 rows of a lane's 8t x 8e partial into a
// stride-68 [32][68] buffer. Lane writes rows i0..i0+3 (kh-split).
// ---------------------------------------------------------------------------
__device__ __forceinline__ void pstore4(float* B, const float (&a)[8][8],
                                        int tg, int eg, int i0) {
#pragma unroll
    for (int ii = 0; ii < 4; ++ii) {
        int i = i0 + ii;
        float* p = B + (tg + 4 * i) * 68 + (eg << 3);
        *(float4*)(p)     = make_float4(a[i][0], a[i][1], a[i][2], a[i][3]);
        *(float4*)(p + 4) = make_float4(a[i][4], a[i][5], a[i][6], a[i][7]);
    }
}
__device__ __forceinline__ void padd4(float* B, const float (&a)[8][8],
                                      int tg, int eg, int i0) {
#pragma unroll
    for (int ii = 0; ii < 4; ++ii) {
        int i = i0 + ii;
        float* p = B + (tg + 4 * i) * 68 + (eg << 3);
        float4 v0 = *(float4*)(p);
        float4 v1 = *(float4*)(p + 4);
        v0.x += a[i][0]; v0.y += a[i][1]; v0.z += a[i][2]; v0.w += a[i][3];
        v1.x += a[i][4]; v1.y += a[i][5]; v1.z += a[i][6]; v1.w += a[i][7];
        *(float4*)(p)     = v0;
        *(float4*)(p + 4) = v1;
    }
}

// ---------------------------------------------------------------------------
// main: TLP-restructured fp32 GEMM. Rounds 0-2 proved the 1024-thread
// single-block-per-CU lockstep is latency-bound (step 7500-9000 cyc vs
// walls ~2-3K) and resistant to intra-block scheduling. Fix: 512 blocks x
// 512 threads (32 tokens each), TWO independent barrier domains per CU
// (LDS 63KB, VGPR<=128) -- one block's stalls are covered by the other.
// w back in LDS (round-2's global-JIT exposed per-step L2 latency).
// Per step (64k): 8 waves x 8k; within a wave lanes kh-split k 2-way so
// every lane keeps the full 8t x 8e tile (1.0 B/FMA, broadcast reads).
// kh halves fold once at the end via __shfl_xor(.,32) -- register-only.
// Single barrier per step, double-buffered x and w slabs (proven shape).
// ---------------------------------------------------------------------------
__launch_bounds__(512, 4)
__global__ void moe_main(const float* __restrict__ x,
                         const float* __restrict__ wt,     // [1024][64]
                         float* __restrict__ acc_ws,
                         float* __restrict__ out) {
    __shared__ float xs[2 * 2176];       // x slabs [32][68] x2; fold scratch
    __shared__ float wl[2 * 4352];       // w slabs [64][68] x2
    __shared__ float sc[32 * 68];        // logits, stride 68
    __shared__ float row_inv[32];
    __shared__ float colpart[8][64];
    __shared__ int   is_last;

    const int tid  = threadIdx.x;
    const int lane = tid & 63;
    const int wv   = __builtin_amdgcn_readfirstlane(tid >> 6);   // 0..7
    const int tg   = lane & 3;           // token sub-row: t = tg + 4i
    const int eg   = (lane >> 2) & 7;    // expert octet: e = eg*8 + j
    const int kh   = lane >> 5;          // k half within step (0/1)
    const int tok0 = blockIdx.x << 5;    // 32 tokens per block

    // ---- staging plan (512 threads)
    // x: 32 rows x 64k = 512 float4 -> 1 per thread
    const int srow = tid >> 4;           // 0..31
    const int sg   = tid & 15;           // 0..15
    const float* gx = x + (((size_t)(tok0 + srow)) << 10) + (sg << 2);
    const int xwloc = srow * 68 + (sg << 2);
    // w: 64 rows x 64e = 1024 float4 -> 2 per thread (rows srow, srow+32)
    const float* gw = wt + (srow << 6) + (sg << 2);
    const int wwloc  = srow * 68 + (sg << 2);
    const int wwloc2 = (srow + 32) * 68 + (sg << 2);

    float acc[8][8];
#pragma unroll
    for (int i = 0; i < 8; ++i)
#pragma unroll
        for (int j = 0; j < 8; ++j) acc[i][j] = 0.f;

    // ---- per-lane read bases
    const int kcol = (kh << 5) + (wv << 2);          // k column within step
    const int xoff = tg * 68 + kcol;                 // + i*272 (imm)
    const int woff = kcol * 68 + (eg << 3);          // + u*68, +4 (imm)

    // ---- prologue: stage step 0 directly; prefetch step 1 into regs
    *(float4*)(xs + xwloc)  = *(const float4*)gx;
    *(float4*)(wl + wwloc)  = *(const float4*)gw;
    *(float4*)(wl + wwloc2) = *(const float4*)(gw + 2048);
    float4 px  = *(const float4*)(gx + 64);
    float4 pw0 = *(const float4*)(gw + 4096);
    float4 pw1 = *(const float4*)(gw + 4096 + 2048);
    __syncthreads();

    int p = 0;
#pragma unroll 1
    for (int s = 0; s < 16; ++s) {
        // store prefetched step s+1 into the alternate slabs
        if (s < 15) {
            const int q = p ^ 1;
            *(float4*)(xs + q * 2176 + xwloc)  = px;
            *(float4*)(wl + q * 4352 + wwloc)  = pw0;
            *(float4*)(wl + q * 4352 + wwloc2) = pw1;
            if (s < 14) {                // issue loads for step s+2
                px  = *(const float4*)(gx + ((s + 2) << 6));
                pw0 = *(const float4*)(gw + ((s + 2) << 12));
                pw1 = *(const float4*)(gw + ((s + 2) << 12) + 2048);
            }
        }
        // compute step s from slabs p
        const float* xr = xs + p * 2176 + xoff;
        const float* wr = wl + p * 4352 + woff;
        float wa[4][8];
#pragma unroll
        for (int u = 0; u < 4; ++u) {
            float4 q0 = *(const float4*)(wr + u * 68);
            float4 q1 = *(const float4*)(wr + u * 68 + 4);
            wa[u][0] = q0.x; wa[u][1] = q0.y; wa[u][2] = q0.z; wa[u][3] = q0.w;
            wa[u][4] = q1.x; wa[u][5] = q1.y; wa[u][6] = q1.z; wa[u][7] = q1.w;
        }
#pragma unroll
        for (int i = 0; i < 8; ++i) {
            float4 xc = *(const float4*)(xr + i * 272);     // x[tg+4i][4k]
            float xa[4] = {xc.x, xc.y, xc.z, xc.w};
#pragma unroll
            for (int u = 0; u < 4; ++u) {
                float xv = xa[u];
#pragma unroll
                for (int j = 0; j < 8; ++j)
                    acc[i][j] = fmaf(xv, wa[u][j], acc[i][j]);
            }
        }
        __syncthreads();                 // reads of p done; writes to p^1 drained
        p ^= 1;
    }

    // ---- intra-wave kh fold (register-only): both halves end with full sums
#pragma unroll
    for (int i = 0; i < 8; ++i)
#pragma unroll
        for (int j = 0; j < 8; ++j)
            acc[i][j] += __shfl_xor(acc[i][j], 32);

    // ---- fold 8 wave-partials into sc via 3 accumulation chains
    const int i0 = kh << 2;              // kh=0 writes rows 0..15, kh=1: 16..31
    float* fb0 = xs;                     // [32][68] scratch
    float* fb1 = xs + 2176;
    if      (wv == 0) pstore4(sc,  acc, tg, eg, i0);
    else if (wv == 1) pstore4(fb0, acc, tg, eg, i0);
    else if (wv == 2) pstore4(fb1, acc, tg, eg, i0);
    __syncthreads();
    if      (wv == 3) padd4(sc,  acc, tg, eg, i0);
    else if (wv == 4) padd4(fb0, acc, tg, eg, i0);
    else if (wv == 5) padd4(fb1, acc, tg, eg, i0);
    __syncthreads();
    if      (wv == 6) padd4(sc,  acc, tg, eg, i0);
    else if (wv == 7) padd4(fb0, acc, tg, eg, i0);
    __syncthreads();
    {   // sc += fb0 + fb1 (vectorized, all 512 threads; 32 rows x 16 granules)
        const int row = tid >> 4, g = tid & 15;
        float* ps = sc + row * 68 + (g << 2);
        float4 a  = *(float4*)ps;
        float4 bx = *(const float4*)(fb0 + row * 68 + (g << 2));
        float4 bw = *(const float4*)(fb1 + row * 68 + (g << 2));
        a.x += bx.x + bw.x; a.y += bx.y + bw.y;
        a.z += bx.z + bw.z; a.w += bx.w + bw.w;
        *(float4*)ps = a;
    }
    __syncthreads();

    // ---- per-token epilogue (serial over 32 tokens, proven code shape)
    if (tid < 32) {
        const int r = tid;
        const float* srow_p = sc + r * 68;
        float v1 = -1e30f, v2 = -1e30f;
        int i1 = 0, i2 = 0;
        for (int j = 0; j < 64; ++j) {
            float l = srow_p[j];
            if (l > v1)      { v2 = v1; i2 = i1; v1 = l; i1 = j; }
            else if (l > v2) { v2 = l; i2 = j; }
        }
        float m = v1;
        float ssum = 0.f;
        for (int j = 0; j < 64; ++j) {
            float ev = expf(srow_p[j] - m);
            ssum += ev;
            sc[r * 68 + j] = ev;
        }
        float inv = 1.f / ssum;
        row_inv[r] = inv;
        float z = m + logf(ssum);
        float zsq = z * z;
#pragma unroll
        for (int off = 16; off > 0; off >>= 1) zsq += __shfl_down(zsq, off);
        if (tid == 0) atomicAdd(acc_ws + 64, zsq);

        float p1s = inv;                        // exp(v1-m) == 1
        float p2s = expf(v2 - m) * inv;
        float bb  = expf(p2s - p1s);
        float s1 = 1.f / (1.f + bb);
        float s2 = bb * s1;
        int t = tok0 + r;
        out[2 * t]     = s1;
        out[2 * t + 1] = s2;
        out[2 * T_TOK + 2 * t]     = (float)i1;
        out[2 * T_TOK + 2 * t + 1] = (float)i2;
    }
    __syncthreads();

    // ---- expert load column sums (8 row-groups of 4 rows)
    {
        int e  = tid & 63;
        int rg = tid >> 6;                      // 0..7
        float sum = 0.f;
#pragma unroll
        for (int r2 = 0; r2 < 4; ++r2) {
            int row = (rg << 2) + r2;
            sum += sc[row * 68 + e] * row_inv[row];
        }
        colpart[rg][e] = sum;
    }
    __syncthreads();
    if (tid < 64) {
        float tot = 0.f;
#pragma unroll
        for (int rg = 0; rg < 8; ++rg) tot += colpart[rg][tid];
        atomicAdd(acc_ws + tid, tot);           // device-scope
    }

    // ---- last-block finalize
    __syncthreads();
    if (tid == 0) {
        __threadfence();
        int old = __hip_atomic_fetch_add((int*)(acc_ws + 66), 1,
                                         __ATOMIC_ACQ_REL, __HIP_MEMORY_SCOPE_AGENT);
        is_last = (old == 511) ? 1 : 0;
    }
    __syncthreads();
    if (is_last && tid < 64) {
        __threadfence();
        float load = __hip_atomic_load(acc_ws + tid, __ATOMIC_RELAXED,
                                       __HIP_MEMORY_SCOPE_AGENT) * (1.f / 16384.f);
        float d = load - (1.f / 64.f);
        float v = d * d;
#pragma unroll
        for (int off = 32; off > 0; off >>= 1) v += __shfl_down(v, off);
        if (tid == 0) {
            float zsum = __hip_atomic_load(acc_ws + 64, __ATOMIC_RELAXED,
                                           __HIP_MEMORY_SCOPE_AGENT);
            float lb = 0.01f * 64.f * v;
            float zl = 1e-4f * zsum * (1.f / 16384.f);
            out[4 * T_TOK] = lb + zl;
        }
    }
}

extern "C" void kernel_launch(void* const* d_in, const int* in_sizes, int n_in,
                              void* d_out, int out_size, void* d_ws, size_t ws_size,
                              hipStream_t stream) {
    const float* x  = (const float*)d_in[0];   // [4,4096,1024] fp32
    const float* gw = (const float*)d_in[1];   // [64,1024] fp32
    float* out = (float*)d_out;                // 65537 fp32
    float* ws  = (float*)d_ws;

    moe_prep<<<16, 256, 0, stream>>>(gw, ws);
    moe_main<<<512, 512, 0, stream>>>(x, ws + 128, ws, out);
}

// Round 4
// 142.163 us; speedup vs baseline: 2.5930x; 2.5930x over previous
//
#include <hip/hip_runtime.h>
#include <math.h>

#define T_TOK 16384   // 4*4096 tokens
#define NEXP  64

// Workspace layout (floats):
//   ws[0..63]   : expert load sums
//   ws[64]      : sum of z^2
//   ws[66]      : block-done counter (int)
//   ws[128 ..]  : w_t transposed gate weights [1024][64]
//
// d_out layout (floats, out_size = 65537):
//   [0, 32768)      top-2 renormalized scores [token][2]
//   [32768, 65536)  top-2 expert indices as floats [token][2]
//   [65536]         total_loss

// ---------------------------------------------------------------------------
// prep: tiled transpose gate_w [64][1024] -> w_t [1024][64]; zero accumulators
// ---------------------------------------------------------------------------
__global__ void moe_prep(const float* __restrict__ gw, float* __restrict__ ws) {
    __shared__ float tile[64][65];
    const int b = blockIdx.x;
    const int tid = threadIdx.x;         // 256
    if (b == 0 && tid < 128) ws[tid] = 0.f;
#pragma unroll
    for (int it = 0; it < 16; ++it) {
        int idx = it * 256 + tid;
        int e = idx >> 6, kk = idx & 63;
        tile[e][kk] = gw[e * 1024 + b * 64 + kk];
    }
    __syncthreads();
#pragma unroll
    for (int it = 0; it < 16; ++it) {
        int idx = it * 256 + tid;
        int kk = idx >> 6, e = idx & 63;
        ws[128 + (b * 64 + kk) * 64 + e] = tile[e][kk];
    }
}

// ---------------------------------------------------------------------------
// main: round-0 proven micro-structure (53.4 us), re-blocked for TLP.
// Round-3 post-mortem: VGPR allocator has been capped at 64 arch-VGPRs all
// along; acc survives in AGPRs (unified file) as long as no cross-lane op
// touches it. Round 3's __shfl_xor(acc) forced acc->VGPR -> scratch spill
// (WRITE_SIZE 336KB -> 1.2GB). This round: NO shuffle on acc, and the only
// change vs round 0 is 32-token blocks (512 thr, 512 blocks) -> TWO
// independent barrier domains per CU. Per-wave work, k-quarter order,
// 2-barrier step, swizzled xbuf, straight wbuf, 4-chain fold, serial
// epilogue: all identical shapes to the proven kernel.
// Waves: wv = te*4 + kq  (te in {0,1}: expert half; kq in 0..3: k-quarter).
// Each wave: 32t x 32e, lane grid 8x8, 4t x 4e per lane.
// ---------------------------------------------------------------------------
__launch_bounds__(512, 2)
__global__ void moe_main(const float* __restrict__ x,
                         const float* __restrict__ wt,     // [1024][64]
                         float* __restrict__ acc_ws,
                         float* __restrict__ out) {
    __shared__ float xbuf[2048];         // x slab: [t 32][chunk 16 ^ swz][4]
    __shared__ float wbuf[4096];         // w slab: [row 64][e 64] straight
    __shared__ float sc[32 * 68];        // logits, stride 68
    __shared__ float row_inv[32];
    __shared__ float colpart[8][64];
    __shared__ int   is_last;

    const int tid  = threadIdx.x;
    const int lane = tid & 63;
    const int wv   = tid >> 6;                                   // 0..7
    const int kq   = __builtin_amdgcn_readfirstlane(wv & 3);     // k quarter
    const int te   = __builtin_amdgcn_readfirstlane(wv >> 2);    // expert half
    const int ta = lane >> 3;            // token-quad within tile (0..7)
    const int eb = lane & 7;             // expert-quad within tile (0..7)
    const int tok0 = blockIdx.x << 5;    // 32 tokens per block

    // ---- staging plan (512 threads, 1 float4 x + 2 float4 w per step)
    // x: thread (srow = token row 0..31, cg): global k = (cg>>2)*256 + s*16 + (cg&3)*4
    const int srow = tid >> 4;           // 0..31
    const int cg   = tid & 15;
    const float* gx = x + (((size_t)(tok0 + srow)) << 10) + ((cg >> 2) << 8) + ((cg & 3) << 2);
    const int xlo = (srow << 6) + ((cg ^ (srow & 15)) << 2);
    // w: slab row r covers global k-row = (r>>4)*256 + s*16 + (r&15)
    //    thread stages rows srow (quarters 0/1) and srow+32 (quarters 2/3)
    const float* gw  = wt + ((((srow >> 4) << 8) + (srow & 15)) << 6) + (cg << 2);
    const float* gw2 = gw + (2 * 256 * 64);
    const int wlo  = (srow << 6) + (cg << 2);
    const int wlo2 = ((srow + 32) << 6) + (cg << 2);

    float acc[16];
#pragma unroll
    for (int e = 0; e < 16; ++e) acc[e] = 0.f;

    // ---- per-lane read bases
    const int t0 = ta << 2;                         // token base (0..28)
    const float* xrow0 = xbuf + ((t0 + 0) << 6);
    const float* xrow1 = xbuf + ((t0 + 1) << 6);
    const float* xrow2 = xbuf + ((t0 + 2) << 6);
    const float* xrow3 = xbuf + ((t0 + 3) << 6);
    const int c0 = (t0 + 0) & 15, c1 = (t0 + 1) & 15;
    const int c2 = (t0 + 2) & 15, c3 = (t0 + 3) & 15;
    const int ebase = (te << 5) + (eb << 2);        // expert base (0..60)
    const float* wp = wbuf + (kq << 10) + ebase;    // + (4*g4+u)*64 (imm)
    const int cwb = kq << 2;                        // x chunk base

    // prologue prefetch of step 0
    float4 px  = *(const float4*)gx;
    float4 pw0 = *(const float4*)gw;
    float4 pw1 = *(const float4*)gw2;

#pragma unroll 1
    for (int s = 0; s < 16; ++s) {
        __syncthreads();                            // bufs free
        *(float4*)(xbuf + xlo)  = px;
        *(float4*)(wbuf + wlo)  = pw0;
        *(float4*)(wbuf + wlo2) = pw1;
        __syncthreads();                            // bufs ready
        if (s < 15) {                               // prefetch next step
            px  = *(const float4*)(gx + ((s + 1) << 4));
            pw0 = *(const float4*)(gw + ((s + 1) << 10));
            pw1 = *(const float4*)(gw2 + ((s + 1) << 10));
        }
#pragma unroll
        for (int g4 = 0; g4 < 4; ++g4) {
            const int cw = cwb + g4;
            float4 xf0 = *(const float4*)(xrow0 + ((cw ^ c0) << 2));
            float4 xf1 = *(const float4*)(xrow1 + ((cw ^ c1) << 2));
            float4 xf2 = *(const float4*)(xrow2 + ((cw ^ c2) << 2));
            float4 xf3 = *(const float4*)(xrow3 + ((cw ^ c3) << 2));
            const float* wq = wp + (g4 << 8);
            float4 wf0 = *(const float4*)(wq);
            float4 wf1 = *(const float4*)(wq + 64);
            float4 wf2 = *(const float4*)(wq + 128);
            float4 wf3 = *(const float4*)(wq + 192);
            float xa[16] = {xf0.x, xf0.y, xf0.z, xf0.w,
                            xf1.x, xf1.y, xf1.z, xf1.w,
                            xf2.x, xf2.y, xf2.z, xf2.w,
                            xf3.x, xf3.y, xf3.z, xf3.w};
            float wa[16] = {wf0.x, wf0.y, wf0.z, wf0.w,
                            wf1.x, wf1.y, wf1.z, wf1.w,
                            wf2.x, wf2.y, wf2.z, wf2.w,
                            wf3.x, wf3.y, wf3.z, wf3.w};
#pragma unroll
            for (int i = 0; i < 4; ++i)
#pragma unroll
                for (int u = 0; u < 4; ++u) {
                    float xv = xa[(i << 2) + u];
#pragma unroll
                    for (int j = 0; j < 4; ++j)
                        acc[(i << 2) + j] = fmaf(xv, wa[(u << 2) + j], acc[(i << 2) + j]);
                }
        }
    }

    // ---- combine 4 k-quarter partials into sc (barrier chain over kq)
    if (kq == 0) {
#pragma unroll
        for (int i = 0; i < 4; ++i) {
            float4 v = make_float4(acc[(i << 2)], acc[(i << 2) + 1],
                                   acc[(i << 2) + 2], acc[(i << 2) + 3]);
            *(float4*)(sc + (t0 + i) * 68 + ebase) = v;
        }
    }
    __syncthreads();
    if (kq == 1) {
#pragma unroll
        for (int i = 0; i < 4; ++i) {
            float4 o = *(float4*)(sc + (t0 + i) * 68 + ebase);
            o.x += acc[(i << 2)];     o.y += acc[(i << 2) + 1];
            o.z += acc[(i << 2) + 2]; o.w += acc[(i << 2) + 3];
            *(float4*)(sc + (t0 + i) * 68 + ebase) = o;
        }
    }
    __syncthreads();
    if (kq == 2) {
#pragma unroll
        for (int i = 0; i < 4; ++i) {
            float4 o = *(float4*)(sc + (t0 + i) * 68 + ebase);
            o.x += acc[(i << 2)];     o.y += acc[(i << 2) + 1];
            o.z += acc[(i << 2) + 2]; o.w += acc[(i << 2) + 3];
            *(float4*)(sc + (t0 + i) * 68 + ebase) = o;
        }
    }
    __syncthreads();
    if (kq == 3) {
#pragma unroll
        for (int i = 0; i < 4; ++i) {
            float4 o = *(float4*)(sc + (t0 + i) * 68 + ebase);
            o.x += acc[(i << 2)];     o.y += acc[(i << 2) + 1];
            o.z += acc[(i << 2) + 2]; o.w += acc[(i << 2) + 3];
            *(float4*)(sc + (t0 + i) * 68 + ebase) = o;
        }
    }
    __syncthreads();

    // ---- per-token epilogue (serial, proven absmax 0)
    if (tid < 32) {
        const int r = tid;
        const float* srow_p = sc + r * 68;
        float v1 = -1e30f, v2 = -1e30f;
        int i1 = 0, i2 = 0;
        for (int j = 0; j < 64; ++j) {
            float l = srow_p[j];
            if (l > v1)      { v2 = v1; i2 = i1; v1 = l; i1 = j; }
            else if (l > v2) { v2 = l; i2 = j; }
        }
        float m = v1;
        float ssum = 0.f;
        for (int j = 0; j < 64; ++j) {
            float ev = expf(srow_p[j] - m);
            ssum += ev;
            sc[r * 68 + j] = ev;
        }
        float inv = 1.f / ssum;
        row_inv[r] = inv;
        float z = m + logf(ssum);
        float zsq = z * z;
#pragma unroll
        for (int off = 16; off > 0; off >>= 1) zsq += __shfl_down(zsq, off);
        if (tid == 0) atomicAdd(acc_ws + 64, zsq);

        float p1s = inv;                        // exp(v1-m) == 1
        float p2s = expf(v2 - m) * inv;
        float bb  = expf(p2s - p1s);
        float s1 = 1.f / (1.f + bb);
        float s2 = bb * s1;
        int t = tok0 + r;
        out[2 * t]     = s1;
        out[2 * t + 1] = s2;
        out[2 * T_TOK + 2 * t]     = (float)i1;
        out[2 * T_TOK + 2 * t + 1] = (float)i2;
    }
    __syncthreads();

    // ---- expert load column sums (8 row-groups of 4 rows)
    {
        int e  = tid & 63;
        int rg = tid >> 6;                      // 0..7
        float sum = 0.f;
#pragma unroll
        for (int r2 = 0; r2 < 4; ++r2) {
            int row = (rg << 2) + r2;
            sum += sc[row * 68 + e] * row_inv[row];
        }
        colpart[rg][e] = sum;
    }
    __syncthreads();
    if (tid < 64) {
        float tot = 0.f;
#pragma unroll
        for (int rg = 0; rg < 8; ++rg) tot += colpart[rg][tid];
        atomicAdd(acc_ws + tid, tot);           // device-scope
    }

    // ---- last-block finalize
    __syncthreads();
    if (tid == 0) {
        __threadfence();
        int old = __hip_atomic_fetch_add((int*)(acc_ws + 66), 1,
                                         __ATOMIC_ACQ_REL, __HIP_MEMORY_SCOPE_AGENT);
        is_last = (old == 511) ? 1 : 0;
    }
    __syncthreads();
    if (is_last && tid < 64) {
        __threadfence();
        float load = __hip_atomic_load(acc_ws + tid, __ATOMIC_RELAXED,
                                       __HIP_MEMORY_SCOPE_AGENT) * (1.f / 16384.f);
        float d = load - (1.f / 64.f);
        float v = d * d;
#pragma unroll
        for (int off = 32; off > 0; off >>= 1) v += __shfl_down(v, off);
        if (tid == 0) {
            float zsum = __hip_atomic_load(acc_ws + 64, __ATOMIC_RELAXED,
                                           __HIP_MEMORY_SCOPE_AGENT);
            float lb = 0.01f * 64.f * v;
            float zl = 1e-4f * zsum * (1.f / 16384.f);
            out[4 * T_TOK] = lb + zl;
        }
    }
}

extern "C" void kernel_launch(void* const* d_in, const int* in_sizes, int n_in,
                              void* d_out, int out_size, void* d_ws, size_t ws_size,
                              hipStream_t stream) {
    const float* x  = (const float*)d_in[0];   // [4,4096,1024] fp32
    const float* gw = (const float*)d_in[1];   // [64,1024] fp32
    float* out = (float*)d_out;                // 65537 fp32
    float* ws  = (float*)d_ws;

    moe_prep<<<16, 256, 0, stream>>>(gw, ws);
    moe_main<<<512, 512, 0, stream>>>(x, ws + 128, ws, out);
}